// Round 3
// baseline (392.517 us; speedup 1.0000x reference)
//
#include <hip/hip_runtime.h>

// Problem constants (from reference)
#define BB   8
#define CC   32
#define TT   960
#define FF   256
#define LDP  24
#define NDP  12
#define NW   40          // TT / LDP
#define DFLAT (NW * FF)  // 10240
#define H1   20          // NW / 2
#define WARM 40          // scan warm-up steps; 0.5^40 ~ 1e-12 truncation

// ---------------------------------------------------------------------------
// K1: channel sum  S[b,t,f] = sum_c spikes[b,c,t,f]   (float4 over f)
// Linear ops commute: scan(mean_c(x)) == mean_c(scan(x)), so we reduce C
// first (32x data reduction before the scan). 4 independent accumulator
// chains -> deep global_load_dwordx4 pipelining.
// ---------------------------------------------------------------------------
__global__ __launch_bounds__(256) void k1_csum(const float4* __restrict__ spikes,
                                               float4* __restrict__ S) {
    const int TF4 = TT * FF / 4;                 // 61440 float4 per (b,c)
    int idx = blockIdx.x * 256 + threadIdx.x;    // exactly B*T*F/4 threads
    int b   = idx / TF4;
    int rem = idx - b * TF4;
    const float4* p = spikes + (size_t)b * CC * TF4 + rem;

    float4 a0 = make_float4(0.f, 0.f, 0.f, 0.f);
    float4 a1 = a0, a2 = a0, a3 = a0;
#pragma unroll
    for (int c = 0; c < CC; c += 4) {
        float4 x0 = p[(size_t)(c + 0) * TF4];
        float4 x1 = p[(size_t)(c + 1) * TF4];
        float4 x2 = p[(size_t)(c + 2) * TF4];
        float4 x3 = p[(size_t)(c + 3) * TF4];
        a0.x += x0.x; a0.y += x0.y; a0.z += x0.z; a0.w += x0.w;
        a1.x += x1.x; a1.y += x1.y; a1.z += x1.z; a1.w += x1.w;
        a2.x += x2.x; a2.y += x2.y; a2.z += x2.z; a2.w += x2.w;
        a3.x += x3.x; a3.y += x3.y; a3.z += x3.z; a3.w += x3.w;
    }
    float4 acc = make_float4((a0.x + a1.x) + (a2.x + a3.x),
                             (a0.y + a1.y) + (a2.y + a3.y),
                             (a0.z + a1.z) + (a2.z + a3.z),
                             (a0.w + a1.w) + (a2.w + a3.w));
    S[(size_t)b * TF4 + rem] = acc;
}

// ---------------------------------------------------------------------------
// K2: leaky-integrator scan (decay 0.5) + differential pooling.
// One wave per (b, window). Warm-up re-scan from 40 steps before the window
// makes windows independent (error ~0.5^40 << fp32 ulp). Three branch-free
// loops: warm-up (no accumulate), first 12 (negative), last 12 (positive).
// dp[b,w,f] = (sum_{pos>=12} v - sum_{pos<12} v) / (12*32) -> d_out
// ---------------------------------------------------------------------------
__global__ __launch_bounds__(256) void k2_scan(const float4* __restrict__ S,
                                               float4* __restrict__ dp) {
    int wid  = blockIdx.x * 4 + (threadIdx.x >> 6);  // 0..319 = b*40 + w
    int lane = threadIdx.x & 63;                     // float4 index over F
    int b = wid / NW;
    int w = wid - b * NW;
    int tstart = w * LDP;
    int t0 = tstart - WARM; if (t0 < 0) t0 = 0;
    const float4* Sb = S + (size_t)b * (TT * FF / 4) + lane;

    float4 v    = make_float4(0.f, 0.f, 0.f, 0.f);
    float4 accN = v, accP = v;

    int t = t0;
    for (; t < tstart; ++t) {                        // warm-up, no accumulate
        float4 x = Sb[(size_t)t * (FF / 4)];
        v.x = v.x * 0.5f + x.x;  v.y = v.y * 0.5f + x.y;
        v.z = v.z * 0.5f + x.z;  v.w = v.w * 0.5f + x.w;
    }
#pragma unroll
    for (int k = 0; k < NDP; ++k, ++t) {             // first 12: negative part
        float4 x = Sb[(size_t)t * (FF / 4)];
        v.x = v.x * 0.5f + x.x;  v.y = v.y * 0.5f + x.y;
        v.z = v.z * 0.5f + x.z;  v.w = v.w * 0.5f + x.w;
        accN.x += v.x; accN.y += v.y; accN.z += v.z; accN.w += v.w;
    }
#pragma unroll
    for (int k = 0; k < NDP; ++k, ++t) {             // last 12: positive part
        float4 x = Sb[(size_t)t * (FF / 4)];
        v.x = v.x * 0.5f + x.x;  v.y = v.y * 0.5f + x.y;
        v.z = v.z * 0.5f + x.z;  v.w = v.w * 0.5f + x.w;
        accP.x += v.x; accP.y += v.y; accP.z += v.z; accP.w += v.w;
    }
    const float scale = 1.0f / (float)(NDP * CC);    // 1/(12*32)
    float4 o = make_float4((accP.x - accN.x) * scale, (accP.y - accN.y) * scale,
                           (accP.z - accN.z) * scale, (accP.w - accN.w) * scale);
    dp[(size_t)(b * NW + w) * (FF / 4) + lane] = o;
}

// ---------------------------------------------------------------------------
// K3: per-batch tiny MLP: h=relu(dp@W1+b1); ta=softmax(h@W2+b2); dp *= ta[w].
// One block per batch, in-place on d_out.
// ---------------------------------------------------------------------------
__global__ __launch_bounds__(256) void k3_mlp(float* __restrict__ dpout,
                                              const float* __restrict__ W1,
                                              const float* __restrict__ b1,
                                              const float* __restrict__ W2,
                                              const float* __restrict__ b2) {
    int b   = blockIdx.x;
    int tid = threadIdx.x;
    float* dp = dpout + (size_t)b * DFLAT;

    __shared__ float red[H1][256];
    __shared__ float ta[NW];

    float acc[H1];
#pragma unroll
    for (int j = 0; j < H1; ++j) acc[j] = 0.f;

    // dp_flat @ W1 : W1 is [DFLAT][H1] row-major; 20 floats = 5 float4 per row
    // (rows are 80 B apart -> every row 16B-aligned)
    for (int d = tid; d < DFLAT; d += 256) {
        float x = dp[d];
        const float4* w1p = (const float4*)(W1 + (size_t)d * H1);
#pragma unroll
        for (int q = 0; q < 5; ++q) {
            float4 wv = w1p[q];
            acc[4*q+0] = fmaf(x, wv.x, acc[4*q+0]);
            acc[4*q+1] = fmaf(x, wv.y, acc[4*q+1]);
            acc[4*q+2] = fmaf(x, wv.z, acc[4*q+2]);
            acc[4*q+3] = fmaf(x, wv.w, acc[4*q+3]);
        }
    }
#pragma unroll
    for (int j = 0; j < H1; ++j) red[j][tid] = acc[j];
    __syncthreads();
    for (int off = 128; off > 0; off >>= 1) {
        if (tid < off) {
#pragma unroll
            for (int j = 0; j < H1; ++j) red[j][tid] += red[j][tid + off];
        }
        __syncthreads();
    }

    if (tid == 0) {
        float h[H1], z[NW];
#pragma unroll
        for (int j = 0; j < H1; ++j) {
            float v = red[j][0] + b1[j];
            h[j] = v > 0.f ? v : 0.f;
        }
#pragma unroll
        for (int k = 0; k < NW; ++k) z[k] = b2[k];
        for (int j = 0; j < H1; ++j) {
            float hj = h[j];
#pragma unroll
            for (int k = 0; k < NW; ++k) z[k] = fmaf(hj, W2[j * NW + k], z[k]);
        }
        float m = z[0];
        for (int k = 1; k < NW; ++k) m = fmaxf(m, z[k]);
        float s = 0.f;
        for (int k = 0; k < NW; ++k) { z[k] = expf(z[k] - m); s += z[k]; }
        float inv = 1.f / s;
        for (int k = 0; k < NW; ++k) ta[k] = z[k] * inv;
    }
    __syncthreads();

    // attended = dp * ta[w];  w = i/256
    for (int i = tid; i < DFLAT; i += 256) {
        dp[i] = dp[i] * ta[i >> 8];
    }
}

extern "C" void kernel_launch(void* const* d_in, const int* in_sizes, int n_in,
                              void* d_out, int out_size, void* d_ws, size_t ws_size,
                              hipStream_t stream) {
    const float* spikes = (const float*)d_in[0];
    const float* W1     = (const float*)d_in[1];
    const float* b1     = (const float*)d_in[2];
    const float* W2     = (const float*)d_in[3];
    const float* b2     = (const float*)d_in[4];
    float* out = (float*)d_out;
    float* S   = (float*)d_ws;   // B*T*F floats = 7.86 MB scratch

    // K1: B*T*F/4 = 491520 float4 outputs -> 1920 blocks x 256
    k1_csum<<<dim3(BB * TT * FF / 4 / 256), dim3(256), 0, stream>>>(
        (const float4*)spikes, (float4*)S);
    // K2: 320 (b,window) waves -> 80 blocks x 256 (4 waves each)
    k2_scan<<<dim3(80), dim3(256), 0, stream>>>(
        (const float4*)S, (float4*)out);
    // K3: one block per batch
    k3_mlp<<<dim3(BB), dim3(256), 0, stream>>>(out, W1, b1, W2, b2);
}

// Round 6
// 382.433 us; speedup vs baseline: 1.0264x; 1.0264x over previous
//
#include <hip/hip_runtime.h>
#include <math.h>

// Problem constants (from reference)
#define BB   8
#define CC   32
#define TT   960
#define FF   256
#define LDP  24
#define NDP  12
#define NW   40          // TT / LDP
#define DFLAT (NW * FF)  // 10240
#define H1   20          // NW / 2
#define WARM 40          // scan warm-up; 0.5^40 ~ 1e-12 truncation (<< fp32 ulp)

// native vector type for __builtin_nontemporal_load (HIP_vector_type rejected)
typedef float float4n __attribute__((ext_vector_type(4)));

// ---------------------------------------------------------------------------
// K1: channel sum  S[b,t,f] = sum_c spikes[b,c,t,f]   (float4 over f)
// Linear ops commute: scan(mean_c(x)) == mean_c(scan(x)) -> 32x reduction
// first. Non-temporal loads: spikes is streamed exactly once, keep it out
// of L2 so S stays resident for K23. 4 accumulator chains for load ILP.
// ---------------------------------------------------------------------------
__global__ __launch_bounds__(256) void k1_csum(const float4n* __restrict__ spikes,
                                               float4n* __restrict__ S) {
    const int TF4 = TT * FF / 4;                 // 61440 float4 per (b,c)
    int idx = blockIdx.x * 256 + threadIdx.x;    // exactly B*T*F/4 threads
    int b   = idx / TF4;
    int rem = idx - b * TF4;
    const float4n* p = spikes + (size_t)b * CC * TF4 + rem;

    float4n a0 = (float4n)0.f, a1 = (float4n)0.f,
            a2 = (float4n)0.f, a3 = (float4n)0.f;
#pragma unroll
    for (int c = 0; c < CC; c += 4) {
        float4n x0 = __builtin_nontemporal_load(&p[(size_t)(c + 0) * TF4]);
        float4n x1 = __builtin_nontemporal_load(&p[(size_t)(c + 1) * TF4]);
        float4n x2 = __builtin_nontemporal_load(&p[(size_t)(c + 2) * TF4]);
        float4n x3 = __builtin_nontemporal_load(&p[(size_t)(c + 3) * TF4]);
        a0 += x0; a1 += x1; a2 += x2; a3 += x3;
    }
    S[(size_t)b * TF4 + rem] = (a0 + a1) + (a2 + a3);
}

// ---------------------------------------------------------------------------
// K23: fused {scan + differential pool} -> LDS dp -> {MLP + softmax + scale}.
// One block per batch (8 blocks x 1024 threads = 16 waves).
// Phase A: wave handles windows w, w+16, w+32; warm-up re-scan from 40 steps
//          before the window (decay 0.5 -> 2^-40 truncation). dp -> LDS.
// Phase B: dp@W1 with per-thread partials, shuffle-reduce per wave, cross-
//          wave via tiny LDS; relu / h@W2 / softmax done wave-parallel in
//          wave 0 via __shfl broadcasts (no serial thread-0 section).
// Phase C: out = dp * ta[w], straight from LDS. dp never touches HBM.
// ---------------------------------------------------------------------------
__global__ __launch_bounds__(1024) void k23_scan_mlp(
        const float4* __restrict__ S, float* __restrict__ out,
        const float* __restrict__ W1, const float* __restrict__ b1,
        const float* __restrict__ W2, const float* __restrict__ b2) {
    int b    = blockIdx.x;
    int tid  = threadIdx.x;
    int wave = tid >> 6;            // 0..15
    int lane = tid & 63;

    __shared__ float dp_s[DFLAT];   // 40 KB: dp[w][f]
    __shared__ float red[16][H1];   // per-wave W1 partials
    __shared__ float ta[NW];

    // ---- Phase A: scan + differential pooling into LDS ----
    const float4* Sb = S + (size_t)b * (TT * FF / 4) + lane;
    const float scale = 1.0f / (float)(NDP * CC);       // 1/(12*32)
    for (int w = wave; w < NW; w += 16) {
        int tstart = w * LDP;
        int t0 = tstart - WARM; if (t0 < 0) t0 = 0;
        float4 v    = make_float4(0.f, 0.f, 0.f, 0.f);
        float4 accN = v, accP = v;
        int t = t0;
        for (; t < tstart; ++t) {                       // warm-up
            float4 x = Sb[(size_t)t * (FF / 4)];
            v.x = v.x * 0.5f + x.x;  v.y = v.y * 0.5f + x.y;
            v.z = v.z * 0.5f + x.z;  v.w = v.w * 0.5f + x.w;
        }
#pragma unroll
        for (int k = 0; k < NDP; ++k, ++t) {            // first 12 (negative)
            float4 x = Sb[(size_t)t * (FF / 4)];
            v.x = v.x * 0.5f + x.x;  v.y = v.y * 0.5f + x.y;
            v.z = v.z * 0.5f + x.z;  v.w = v.w * 0.5f + x.w;
            accN.x += v.x; accN.y += v.y; accN.z += v.z; accN.w += v.w;
        }
#pragma unroll
        for (int k = 0; k < NDP; ++k, ++t) {            // last 12 (positive)
            float4 x = Sb[(size_t)t * (FF / 4)];
            v.x = v.x * 0.5f + x.x;  v.y = v.y * 0.5f + x.y;
            v.z = v.z * 0.5f + x.z;  v.w = v.w * 0.5f + x.w;
            accP.x += v.x; accP.y += v.y; accP.z += v.z; accP.w += v.w;
        }
        float4 o = make_float4((accP.x - accN.x) * scale,
                               (accP.y - accN.y) * scale,
                               (accP.z - accN.z) * scale,
                               (accP.w - accN.w) * scale);
        ((float4*)dp_s)[w * (FF / 4) + lane] = o;
    }
    __syncthreads();

    // ---- Phase B: h = relu(dp@W1 + b1); ta = softmax(h@W2 + b2) ----
    float acc[H1];
#pragma unroll
    for (int j = 0; j < H1; ++j) acc[j] = 0.f;
    for (int d = tid; d < DFLAT; d += 1024) {           // 10 iters
        float x = dp_s[d];
        const float4* w1p = (const float4*)(W1 + (size_t)d * H1); // 80B rows, 16B-aligned
#pragma unroll
        for (int q = 0; q < 5; ++q) {
            float4 wv = w1p[q];
            acc[4*q+0] = fmaf(x, wv.x, acc[4*q+0]);
            acc[4*q+1] = fmaf(x, wv.y, acc[4*q+1]);
            acc[4*q+2] = fmaf(x, wv.z, acc[4*q+2]);
            acc[4*q+3] = fmaf(x, wv.w, acc[4*q+3]);
        }
    }
#pragma unroll
    for (int j = 0; j < H1; ++j) {                      // wave shuffle-reduce
        float v = acc[j];
#pragma unroll
        for (int off = 32; off > 0; off >>= 1) v += __shfl_down(v, off);
        if (lane == 0) red[wave][j] = v;
    }
    __syncthreads();

    if (wave == 0) {
        // lane j<20 owns h[j]
        float h_own = 0.f;
        if (lane < H1) {
#pragma unroll
            for (int w = 0; w < 16; ++w) h_own += red[w][lane];
            h_own += b1[lane];
            h_own = h_own > 0.f ? h_own : 0.f;
        }
        // lane k<40 owns z[k]; broadcast h[j] via shuffles
        float z = -INFINITY;
        if (lane < NW) z = b2[lane];
#pragma unroll
        for (int j = 0; j < H1; ++j) {
            float hj = __shfl(h_own, j);
            if (lane < NW) z = fmaf(hj, W2[j * NW + lane], z);
        }
        float m = z;
#pragma unroll
        for (int off = 32; off > 0; off >>= 1) m = fmaxf(m, __shfl_xor(m, off));
        float e = (lane < NW) ? expf(z - m) : 0.f;
        float s = e;
#pragma unroll
        for (int off = 32; off > 0; off >>= 1) s += __shfl_xor(s, off);
        if (lane < NW) ta[lane] = e / s;
    }
    __syncthreads();

    // ---- Phase C: attended = dp * ta[w] ----
    float* ob = out + (size_t)b * DFLAT;
    for (int i = tid; i < DFLAT; i += 1024)
        ob[i] = dp_s[i] * ta[i >> 8];
}

extern "C" void kernel_launch(void* const* d_in, const int* in_sizes, int n_in,
                              void* d_out, int out_size, void* d_ws, size_t ws_size,
                              hipStream_t stream) {
    const float* spikes = (const float*)d_in[0];
    const float* W1     = (const float*)d_in[1];
    const float* b1     = (const float*)d_in[2];
    const float* W2     = (const float*)d_in[3];
    const float* b2     = (const float*)d_in[4];
    float* out = (float*)d_out;
    float* S   = (float*)d_ws;   // B*T*F floats = 7.86 MB scratch

    // K1: B*T*F/4 = 491520 float4 outputs -> 1920 blocks x 256
    k1_csum<<<dim3(BB * TT * FF / 4 / 256), dim3(256), 0, stream>>>(
        (const float4n*)spikes, (float4n*)S);
    // K23: one block per batch, 16 waves each
    k23_scan_mlp<<<dim3(BB), dim3(1024), 0, stream>>>(
        (const float4*)S, out, W1, b1, W2, b2);
}